// Round 7
// baseline (199.395 us; speedup 1.0000x reference)
//
#include <hip/hip_runtime.h>

// LIF net on MI355X.  Split-stream pipeline (batch-quarters to fit ws):
//  1. convert_W: Bt[13][256][64] bf16 (relu, slot-swizzled, K-pad 832) + wrelu
//  2. convert_A (per quarter): spikes fp32 -> At bf16 MFMA-tile layout
//     [bq][t0b][kt][64m][8slot][8k], slot = koct ^ (m&7)  (swizzle baked)
//  3. gemm_hidden (per quarter): A-stage = 1 linear gload16/thr/iter,
//     B-stage = 4; BK=64 dbuf, counted vmcnt(5); -> Ih[b][h][512] bf16
//  4. scan_h: wave-per-row parallel LIF scan (shfl_up affine composition)
//  5. out_fused: per-b VALU dot (K=256,N=10) -> LDS -> segmented v_o scan
// ws: wrelu @0 | Bt @16KB | At_q @512KB (27.3MB) | Ih @28MB (33.55MB) = 62MB

typedef __attribute__((ext_vector_type(4))) float  floatx4;
typedef __attribute__((ext_vector_type(8))) short  shortx8;
typedef unsigned short u16;
typedef unsigned int   u32;

#define B_   128
#define NIN  784
#define NH   256
#define NO   10
#define T_   500
#define KT   13            // k64-tiles (K padded to 832)

__device__ __forceinline__ u16 f2bf(float f) {
    union { float f; u32 u; } x; x.f = f;
    u32 r = x.u + 0x7FFFu + ((x.u >> 16) & 1u);   // RNE
    return (u16)(r >> 16);
}
__device__ __forceinline__ float bf2f(u16 u) {
    union { u32 u; float f; } x; x.u = ((u32)u) << 16; return x.f;
}
__device__ __forceinline__ float sigmoid5(float v) {
    return 1.0f / (1.0f + __expf(-5.0f * (v - 1.0f)));
}
__device__ __forceinline__ int swz8(int r) { return (r & 7) ^ ((r >> 3) & 7); }

__device__ __forceinline__ void gload16(const u16* g, u16* l) {
    __builtin_amdgcn_global_load_lds(
        (const __attribute__((address_space(1))) unsigned int*)(const void*)g,
        (__attribute__((address_space(3))) unsigned int*)(void*)l, 16, 0, 0);
}

// ---------- Pre-pass: Bt[kt][n][slot] bf16 (relu, swizzled) + wrelu ----------
__global__ void convert_W(const float* __restrict__ w_ih,
                          const float* __restrict__ w_ho,
                          u16* __restrict__ Bt, float* __restrict__ wrelu) {
    if (blockIdx.x == KT * 64) {
        for (int i = threadIdx.x; i < NH * NO; i += 256)
            wrelu[i] = fmaxf(0.f, w_ho[i]);
        return;
    }
    const int k = blockIdx.x;           // 0..831
    const int n = threadIdx.x;          // 0..255
    const float f = (k < NIN) ? fmaxf(0.f, w_ih[k * NH + n]) : 0.f;
    const int kt = k >> 6, kk = k & 63;
    Bt[(size_t)kt * 16384 + n * 64 + (kk ^ (swz8(n) << 3))] = f2bf(f);
}

// ---------- Stream kernel: spikes fp32 -> At bf16 MFMA tiles ----------
// Block = (bq, t0b, kt): 8KB output tile [64m][8s][8k], s = koct ^ (m&7).
// Read coalesced along t; LDS [64k][66t-pad] fp32; write linear 16B granules.
__global__ __launch_bounds__(256) void convert_A(
    const float* __restrict__ spikes, u16* __restrict__ AtQ, int b0)
{
    __shared__ float L[64][66];
    const int bid = blockIdx.x;                 // 32*8*13 = 3328
    const int kt  = bid % KT;
    const int rem = bid / KT;
    const int t0b = rem & 7, bq = rem >> 3;
    const int b  = b0 + bq;
    const int k0 = kt * 64, t0 = t0b * 64;
    const int tid = threadIdx.x;

    // read: 64 k-rows x 64 t; thread (kk=tid>>2, qq=tid&3) does 2 passes
    const int kk = tid >> 2, qq = tid & 3;
    const int gk = k0 + kk;
    const bool okk = (gk < NIN);
    const float* row = spikes + (size_t)b * (NIN * T_) + (size_t)(okk ? gk : 0) * T_;
#pragma unroll
    for (int p = 0; p < 2; ++p) {
        const int t = t0 + p * 32 + qq * 8;
        const bool ok0 = okk && (t < T_);       // starts are 0 mod 4; <500 <=> valid
        const bool ok1 = okk && (t + 4 < T_);
        floatx4 v0 = *(const floatx4*)(row + (ok0 ? t : 0));
        floatx4 v1 = *(const floatx4*)(row + (ok1 ? t + 4 : 0));
        if (!ok0) v0 = (floatx4)0.f;
        if (!ok1) v1 = (floatx4)0.f;
        *(floatx4*)&L[kk][p * 32 + qq * 8]     = v0;
        *(floatx4*)&L[kk][p * 32 + qq * 8 + 4] = v1;
    }
    __syncthreads();

    // write: 512 granules; thread does 2.  granule G: m=G>>3, s=G&7,
    // octet g = s ^ (m&7); gather 8 k, pack, one 16B store (linear in G).
    u16* dst = AtQ + ((size_t)bid << 12);       // *4096 u16
#pragma unroll
    for (int g2 = 0; g2 < 2; ++g2) {
        const int G = g2 * 256 + tid;
        const int m = G >> 3, s = G & 7;
        const int g = s ^ (m & 7);
        shortx8 pk;
#pragma unroll
        for (int j = 0; j < 8; ++j)
            pk[j] = (short)f2bf(L[g * 8 + j][m]);
        *(shortx8*)(dst + G * 8) = pk;
    }
}

// ---------- hidden GEMM: both operands pre-tiled, pure gload16 staging ----------
// 256 blocks/quarter = (bq, t0b).  512 thr (8 waves 2x4), wave tile 32x64.
// As 2x8KB + Bs 2x64KB... Bs 2x32KB; LDS total 80KB -> 2 blocks/CU capacity.
__global__ __launch_bounds__(512, 4) void gemm_hidden(
    const u16* __restrict__ AtQ,        // [bq*8+t0b][13][4096]
    const u16* __restrict__ Bt,         // [13][256][64]
    u16* __restrict__ IhQ)              // [32 b][256 n][512 t]
{
    __shared__ u16 As[2][64 * 64];      // 8KB x2
    __shared__ u16 Bs[2][256 * 64];     // 32KB x2 (Cs reuses Bs[0])

    const int tid = threadIdx.x;
    const int bq  = blockIdx.x >> 3, t0b = blockIdx.x & 7;
    const u16* Abase = AtQ + ((size_t)(blockIdx.x) * KT << 12);

#define STAGEA(i) gload16(Abase + ((size_t)(i) << 12) + tid * 8,               \
                          &As[(i) & 1][tid * 8]);
#define STAGEB(i) { const u16* src = Bt + (size_t)(i) * 16384;                 \
        _Pragma("unroll") for (int c = 0; c < 4; ++c)                          \
            gload16(src + c * 4096 + tid * 8, &Bs[(i) & 1][c * 4096 + tid * 8]); }

    const int lane = tid & 63, wid = tid >> 6;
    const int wm = wid >> 2, wn = wid & 3;
    const int lg = lane >> 4, lr = lane & 15;
    int aBase[2], mx[2], bOff[4];
#pragma unroll
    for (int mi = 0; mi < 2; ++mi) {
        const int m = wm * 32 + mi * 16 + lr;
        aBase[mi] = m * 64;  mx[mi] = m & 7;
    }
#pragma unroll
    for (int ni = 0; ni < 4; ++ni) {
        const int n = wn * 64 + ni * 16 + lr;
        bOff[ni] = n * 64 + ((lg * 8) ^ (swz8(n) << 3));
    }

    floatx4 acc[2][4];
#pragma unroll
    for (int i = 0; i < 2; ++i)
#pragma unroll
        for (int j = 0; j < 4; ++j) acc[i][j] = (floatx4)0.f;

#define MFMAI(buf) { _Pragma("unroll") for (int ks = 0; ks < 2; ++ks) {        \
        shortx8 af[2], bfv[4];                                                 \
        _Pragma("unroll") for (int mi = 0; mi < 2; ++mi)                       \
            af[mi] = *(const shortx8*)&As[buf][aBase[mi] +                     \
                        ((((ks * 4 + lg)) ^ mx[mi]) << 3)];                    \
        _Pragma("unroll") for (int ni = 0; ni < 4; ++ni)                       \
            bfv[ni] = *(const shortx8*)&Bs[buf][bOff[ni] ^ (ks * 32)];         \
        _Pragma("unroll") for (int mi = 0; mi < 2; ++mi)                       \
        _Pragma("unroll") for (int ni = 0; ni < 4; ++ni)                       \
            acc[mi][ni] = __builtin_amdgcn_mfma_f32_16x16x32_bf16(             \
                af[mi], bfv[ni], acc[mi][ni], 0, 0, 0); } }

#define LGKM0 asm volatile("s_waitcnt lgkmcnt(0)" ::: "memory");
#define SBARX __builtin_amdgcn_s_barrier();

    // prologue: [A0 B0x4 A1 B1x4] outstanding=10; tile0 ready at vmcnt(5)
    STAGEA(0) STAGEB(0) STAGEA(1) STAGEB(1)
    asm volatile("s_waitcnt vmcnt(5)" ::: "memory");
    SBARX

#define BODY(i)                                                                \
    MFMAI((i) & 1)                                                             \
    LGKM0 SBARX                                                                \
    STAGEA((i) + 2) STAGEB((i) + 2)                                            \
    asm volatile("s_waitcnt vmcnt(5)" ::: "memory");                           \
    SBARX

    BODY(0) BODY(1) BODY(2) BODY(3) BODY(4) BODY(5)
    BODY(6) BODY(7) BODY(8) BODY(9) BODY(10)

    MFMAI(1)                            // tile 11
    LGKM0 SBARX
    asm volatile("s_waitcnt vmcnt(0)" ::: "memory");
    SBARX
    MFMAI(0)                            // tile 12
    LGKM0 SBARX                         // Bs[0] free for Cs

    // epilogue: transpose via Cs -> IhQ[bq][n][t0 + m]
    u16* Cs = &Bs[0][0];                // [256][64] u16
#pragma unroll
    for (int mi = 0; mi < 2; ++mi)
#pragma unroll
        for (int r = 0; r < 4; ++r) {
            const int m = wm * 32 + mi * 16 + lg * 4 + r;
#pragma unroll
            for (int ni = 0; ni < 4; ++ni) {
                const int n = wn * 64 + ni * 16 + lr;
                Cs[n * 64 + (m ^ ((n & 7) << 3))] = f2bf(acc[mi][ni][r]);
            }
        }
    LGKM0 SBARX
    {
        const int n  = tid >> 1, mh = tid & 1;
        u16* gdst = IhQ + ((size_t)bq * 256 + n) * 512 + t0b * 64 + mh * 32;
#pragma unroll
        for (int j = 0; j < 4; ++j) {
            const uint4 v = *(const uint4*)&Cs[n * 64 + ((mh * 32 + 8 * j) ^ ((n & 7) << 3))];
            *(uint4*)(gdst + 8 * j) = v;
        }
    }
#undef STAGEA
#undef STAGEB
#undef MFMAI
#undef LGKM0
#undef SBARX
#undef BODY
}

// ---------- parallel hidden LIF scan (in place) ----------
__global__ __launch_bounds__(512) void scan_h(u16* __restrict__ Ih) {
    const int lane = threadIdx.x & 63;
    const int row  = blockIdx.x * 8 + (threadIdx.x >> 6);
    u16* p = Ih + (size_t)row * 512 + lane * 8;
    shortx8 xv = *(const shortx8*)p;
    float I[8];
#pragma unroll
    for (int j = 0; j < 8; ++j) I[j] = bf2f((u16)xv[j]);
    float z = 0.f;
#pragma unroll
    for (int j = 0; j < 8; ++j) z += (I[j] - z) * 0.1f;
    float A = 0.43046721f, Bv = z;                 // 0.9^8
#pragma unroll
    for (int d = 1; d < 64; d <<= 1) {
        const float Au = __shfl_up(A, d);
        const float Bu = __shfl_up(Bv, d);
        if (lane >= d) { Bv = fmaf(A, Bu, Bv); A *= Au; }
    }
    float v = __shfl_up(Bv, 1);
    if (lane == 0) v = 0.f;
#pragma unroll
    for (int j = 0; j < 8; ++j) {
        v += (I[j] - v) * 0.1f;
        xv[j] = (short)f2bf(sigmoid5(v));
    }
    *(shortx8*)p = xv;
}

// ---------- output dot + segmented v_o scan ----------
__global__ __launch_bounds__(512) void out_fused(
    const u16* __restrict__ s,          // [128][256][512] bf16
    const float* __restrict__ wr,       // [256][10] relu'd f32
    float* __restrict__ out)
{
    __shared__ float Io[T_ * NO];
    __shared__ float vend[25][NO], vstart[25][NO], psum[25][NO];
    const int b = blockIdx.x, tid = threadIdx.x;

    float acc[NO];
#pragma unroll
    for (int o = 0; o < NO; ++o) acc[o] = 0.f;
    const u16* sb = s + (size_t)b * NH * 512 + tid;
#pragma unroll 2
    for (int h = 0; h < NH; ++h) {
        const float sv = bf2f(sb[h * 512]);
#pragma unroll
        for (int o = 0; o < NO; ++o) acc[o] = fmaf(sv, wr[h * NO + o], acc[o]);
    }
    if (tid < T_) {
#pragma unroll
        for (int o = 0; o < NO; ++o) Io[tid * NO + o] = acc[o];
    }
    __syncthreads();

    const int seg = tid / NO, o = tid - seg * NO;
    if (tid < 250) {
        float v = 0.f;
#pragma unroll
        for (int j = 0; j < 20; ++j)
            v += (Io[(seg * 20 + j) * NO + o] - v) * 0.1f;
        vend[seg][o] = v;
    }
    __syncthreads();
    if (tid < NO) {
        float vs = 0.f;
#pragma unroll
        for (int sg = 0; sg < 25; ++sg) {
            vstart[sg][tid] = vs;
            vs = vend[sg][tid] + 0.12157665459f * vs;   // 0.9^20
        }
    }
    __syncthreads();
    if (tid < 250) {
        float v = vstart[seg][o], ps = 0.f;
#pragma unroll
        for (int j = 0; j < 20; ++j) {
            const int t = seg * 20 + j;
            v += (Io[t * NO + o] - v) * 0.1f;
            const float sv = sigmoid5(v);
            out[(size_t)b * (NO * T_) + (size_t)o * T_ + t] = sv;
            ps += sv;
        }
        psum[seg][o] = ps;
    }
    __syncthreads();
    if (tid < NO) {
        float tot = 0.f;
#pragma unroll
        for (int sg = 0; sg < 25; ++sg) tot += psum[sg][tid];
        out[(size_t)(B_ * NO) * T_ + b * NO + tid] = tot * (1.0f / T_);
    }
}

extern "C" void kernel_launch(void* const* d_in, const int* in_sizes, int n_in,
                              void* d_out, int out_size, void* d_ws, size_t ws_size,
                              hipStream_t stream) {
    (void)in_sizes; (void)n_in; (void)out_size; (void)ws_size;
    const float* spikes = (const float*)d_in[0];   // [128][784][500]
    const float* w_ih   = (const float*)d_in[1];   // [784][256]
    const float* w_ho   = (const float*)d_in[2];   // [256][10]
    float* out = (float*)d_out;

    float* wrelu = (float*)d_ws;                              // 10KB @0
    u16*   Bt    = (u16*)((char*)d_ws + 16384);               // 416KB
    u16*   AtQ   = (u16*)((char*)d_ws + 524288);              // 27.3MB
    u16*   Ih    = (u16*)((char*)d_ws + 29360128);            // 33.55MB

    convert_W<<<KT * 64 + 1, 256, 0, stream>>>(w_ih, w_ho, Bt, wrelu);
    for (int q = 0; q < 4; ++q) {
        convert_A  <<<3328, 256, 0, stream>>>(spikes, AtQ, q * 32);
        gemm_hidden<<<256, 512, 0, stream>>>(AtQ, Bt,
                                             Ih + (size_t)q * 32 * NH * 512);
    }
    scan_h   <<<4096, 512, 0, stream>>>(Ih);
    out_fused<<<B_, 512, 0, stream>>>(Ih, wrelu, out);
}

// Round 8
// 158.956 us; speedup vs baseline: 1.2544x; 1.2544x over previous
//
#include <hip/hip_runtime.h>

// LIF net on MI355X.  Bulk-phase fused pipeline:
//  1. convert_W: Bt[7][256][128] bf16 (relu, swizzled, K-pad 896) + wrelu f32
//  2. gemm_hidden: 256 blocks (b, t-half), tile 256m x 256n, K = 7 slabs of
//     128.  Per phase: bulk-stream A (128KB fp32 -> reg transpose/cvt ->
//     swizzled LDS) overlapped with B gload16 (64KB); 2 barriers; 128 MFMA
//     per wave.  Read-once A.  Epilogue transpose -> Ih[b][h][512] bf16.
//  3. scan_h: wave-per-row parallel LIF scan (shfl_up affine composition)
//  4. out_fused: per-b VALU dot (K=256,N=10) -> LDS -> segmented v_o scan
// ws: wrelu @0 | Bt @16KB (448KB) | Ih @512KB (33.55MB)

typedef __attribute__((ext_vector_type(4))) float  floatx4;
typedef __attribute__((ext_vector_type(8))) short  shortx8;
typedef unsigned short u16;
typedef unsigned int   u32;

#define B_   128
#define NIN  784
#define NH   256
#define NO   10
#define T_   500
#define NSLAB 7            // K padded to 896, slabs of 128

__device__ __forceinline__ u16 f2bf(float f) {
    union { float f; u32 u; } x; x.f = f;
    u32 r = x.u + 0x7FFFu + ((x.u >> 16) & 1u);   // RNE
    return (u16)(r >> 16);
}
__device__ __forceinline__ float bf2f(u16 u) {
    union { u32 u; float f; } x; x.u = ((u32)u) << 16; return x.f;
}
__device__ __forceinline__ float sigmoid5(float v) {
    return 1.0f / (1.0f + __expf(-5.0f * (v - 1.0f)));
}

__device__ __forceinline__ void gload16(const u16* g, u16* l) {
    __builtin_amdgcn_global_load_lds(
        (const __attribute__((address_space(1))) unsigned int*)(const void*)g,
        (__attribute__((address_space(3))) unsigned int*)(void*)l, 16, 0, 0);
}

// ---------- Pre-pass: Bt[slab][n][kk^((n&7)<<3)] bf16 + wrelu ----------
__global__ void convert_W(const float* __restrict__ w_ih,
                          const float* __restrict__ w_ho,
                          u16* __restrict__ Bt, float* __restrict__ wrelu) {
    if (blockIdx.x == NSLAB * 128) {
        for (int i = threadIdx.x; i < NH * NO; i += 256)
            wrelu[i] = fmaxf(0.f, w_ho[i]);
        return;
    }
    const int k = blockIdx.x;           // 0..895
    const int n = threadIdx.x;          // 0..255
    const float f = (k < NIN) ? fmaxf(0.f, w_ih[k * NH + n]) : 0.f;
    const int slab = k >> 7, kk = k & 127;
    Bt[(size_t)slab * 32768 + n * 128 + (kk ^ ((n & 7) << 3))] = f2bf(f);
}

// ---------- hidden GEMM: bulk phases, read-once A ----------
// 256 blocks = (b, thalf); 512 thr = 8 waves (4 wm x 2 wn), wave tile
// 64m x 128n (4x8 frags, 128 acc VGPR).  LDS: As[256][128] 64KB +
// Bs[256][128] 64KB (epilogue reuses both as Cs[256][256]).
__global__ __launch_bounds__(512, 2) void gemm_hidden(
    const float* __restrict__ spikes,   // [128][784][500] f32
    const u16* __restrict__ Bt,         // [7][256][128] bf16 swizzled
    u16* __restrict__ Ih)               // [128][256][512] bf16
{
    __shared__ u16 SH[65536];           // 128KB: As=SH[0..], Bs=SH[32768..]
    u16* As = SH;
    u16* Bs = SH + 32768;

    const int tid   = threadIdx.x;
    const int b     = blockIdx.x >> 1;
    const int thalf = blockIdx.x & 1;

    // staging role: thread = (kp 0..63, tq 0..7); covers k=2kp,2kp+1 at
    // t = thalf*256 + tq*32 .. +31  (two 128B contiguous runs per k-row)
    const int kp = tid & 63, tq = tid >> 6;
    const int tbase = tq * 32;                         // local within tile
    const int tglob = thalf * 256 + tbase;
    const float* sbase = spikes + (size_t)b * (NIN * T_);

    // MFMA roles
    const int lane = tid & 63, wid = tid >> 6;
    const int wm = wid >> 1, wn = wid & 1;             // wm 0..3, wn 0..1
    const int lg = lane >> 4, lr = lane & 15;
    const int sx = (lr & 7) << 3;                      // frag XOR (u16 units)
    int aRow[4], bRow[8];
#pragma unroll
    for (int mi = 0; mi < 4; ++mi) aRow[mi] = (wm * 64 + mi * 16 + lr) * 128;
#pragma unroll
    for (int ni = 0; ni < 8; ++ni) bRow[ni] = (wn * 128 + ni * 16 + lr) * 128;

    floatx4 acc[4][8];
#pragma unroll
    for (int i = 0; i < 4; ++i)
#pragma unroll
        for (int j = 0; j < 8; ++j) acc[i][j] = (floatx4)0.f;

    for (int p = 0; p < NSLAB; ++p) {
        // ---- issue B stage first (transfer rides under A stream) ----
        {
            const u16* src = Bt + (size_t)p * 32768;
#pragma unroll
            for (int c = 0; c < 8; ++c)
                gload16(src + c * 4096 + tid * 8, Bs + c * 4096 + tid * 8);
        }
        // ---- bulk A stream: 2 k-rows x 32 t, clamp+select guards ----
        floatx4 va[2][8];
#pragma unroll
        for (int r = 0; r < 2; ++r) {
            const int gk = p * 128 + 2 * kp + r;
            const bool okk = (gk < NIN);
            const float* row = sbase + (size_t)(okk ? gk : 0) * T_;
#pragma unroll
            for (int j = 0; j < 8; ++j) {
                const int tj = tglob + j * 4;
                const bool ok = okk && (tj < T_);
                floatx4 v = *(const floatx4*)(row + (tj < T_ ? tj : 496));
                va[r][j] = ok ? v : (floatx4)0.f;
            }
        }
        // ---- convert + pack k-pairs -> swizzled As ----
#pragma unroll
        for (int j = 0; j < 8; ++j)
#pragma unroll
            for (int q = 0; q < 4; ++q) {
                const int row = tbase + j * 4 + q;
                const u32 pk = (u32)f2bf(va[0][j][q]) | ((u32)f2bf(va[1][j][q]) << 16);
                *(u32*)&As[row * 128 + ((2 * kp) ^ ((row & 7) << 3))] = pk;
            }
        __syncthreads();   // drains A ds_writes + B gload16s

        // ---- MFMA: 4 k32-steps x (4 A-frags, 8 B-frags, 32 mfma) ----
#pragma unroll
        for (int ks = 0; ks < 4; ++ks) {
            const int ko = ks * 32 + lg * 8;
            shortx8 af[4], bf[8];
#pragma unroll
            for (int mi = 0; mi < 4; ++mi)
                af[mi] = *(const shortx8*)&As[aRow[mi] + (ko ^ sx)];
#pragma unroll
            for (int ni = 0; ni < 8; ++ni)
                bf[ni] = *(const shortx8*)&Bs[bRow[ni] + (ko ^ sx)];
#pragma unroll
            for (int mi = 0; mi < 4; ++mi)
#pragma unroll
                for (int ni = 0; ni < 8; ++ni)
                    acc[mi][ni] = __builtin_amdgcn_mfma_f32_16x16x32_bf16(
                        af[mi], bf[ni], acc[mi][ni], 0, 0, 0);
        }
        __syncthreads();   // As/Bs free for next slab
    }

    // ---- epilogue: Cs[256 n][256 m] transpose -> Ih[b][n][thalf*256+m] ----
    u16* Cs = SH;          // 128KB
#pragma unroll
    for (int mi = 0; mi < 4; ++mi) {
        const int m0 = wm * 64 + mi * 16 + lg * 4;
#pragma unroll
        for (int rr = 0; rr < 2; ++rr) {
#pragma unroll
            for (int ni = 0; ni < 8; ++ni) {
                const int n = wn * 128 + ni * 16 + lr;
                const u32 pk = (u32)f2bf(acc[mi][ni][rr * 2]) |
                               ((u32)f2bf(acc[mi][ni][rr * 2 + 1]) << 16);
                *(u32*)&Cs[n * 256 + ((m0 + 2 * rr) ^ ((n & 7) << 3))] = pk;
            }
        }
    }
    __syncthreads();
    {
        const int n = tid >> 1, mh = tid & 1;
        u16* gdst = Ih + ((size_t)b * 256 + n) * 512 + thalf * 256 + mh * 128;
#pragma unroll
        for (int j = 0; j < 16; ++j) {
            const uint4 v = *(const uint4*)&Cs[n * 256 + ((mh * 128 + 8 * j) ^ ((n & 7) << 3))];
            *(uint4*)(gdst + 8 * j) = v;
        }
    }
}

// ---------- parallel hidden LIF scan (in place) ----------
__global__ __launch_bounds__(512) void scan_h(u16* __restrict__ Ih) {
    const int lane = threadIdx.x & 63;
    const int row  = blockIdx.x * 8 + (threadIdx.x >> 6);
    u16* p = Ih + (size_t)row * 512 + lane * 8;
    shortx8 xv = *(const shortx8*)p;
    float I[8];
#pragma unroll
    for (int j = 0; j < 8; ++j) I[j] = bf2f((u16)xv[j]);
    float z = 0.f;
#pragma unroll
    for (int j = 0; j < 8; ++j) z += (I[j] - z) * 0.1f;
    float A = 0.43046721f, Bv = z;                 // 0.9^8
#pragma unroll
    for (int d = 1; d < 64; d <<= 1) {
        const float Au = __shfl_up(A, d);
        const float Bu = __shfl_up(Bv, d);
        if (lane >= d) { Bv = fmaf(A, Bu, Bv); A *= Au; }
    }
    float v = __shfl_up(Bv, 1);
    if (lane == 0) v = 0.f;
#pragma unroll
    for (int j = 0; j < 8; ++j) {
        v += (I[j] - v) * 0.1f;
        xv[j] = (short)f2bf(sigmoid5(v));
    }
    *(shortx8*)p = xv;
}

// ---------- output dot + segmented v_o scan ----------
__global__ __launch_bounds__(512) void out_fused(
    const u16* __restrict__ s,          // [128][256][512] bf16
    const float* __restrict__ wr,       // [256][10] relu'd f32
    float* __restrict__ out)
{
    __shared__ float Io[T_ * NO];
    __shared__ float vend[25][NO], vstart[25][NO], psum[25][NO];
    const int b = blockIdx.x, tid = threadIdx.x;

    float acc[NO];
#pragma unroll
    for (int o = 0; o < NO; ++o) acc[o] = 0.f;
    const u16* sb = s + (size_t)b * NH * 512 + tid;
#pragma unroll 2
    for (int h = 0; h < NH; ++h) {
        const float sv = bf2f(sb[h * 512]);
#pragma unroll
        for (int o = 0; o < NO; ++o) acc[o] = fmaf(sv, wr[h * NO + o], acc[o]);
    }
    if (tid < T_) {
#pragma unroll
        for (int o = 0; o < NO; ++o) Io[tid * NO + o] = acc[o];
    }
    __syncthreads();

    const int seg = tid / NO, o = tid - seg * NO;
    if (tid < 250) {
        float v = 0.f;
#pragma unroll
        for (int j = 0; j < 20; ++j)
            v += (Io[(seg * 20 + j) * NO + o] - v) * 0.1f;
        vend[seg][o] = v;
    }
    __syncthreads();
    if (tid < NO) {
        float vs = 0.f;
#pragma unroll
        for (int sg = 0; sg < 25; ++sg) {
            vstart[sg][tid] = vs;
            vs = vend[sg][tid] + 0.12157665459f * vs;   // 0.9^20
        }
    }
    __syncthreads();
    if (tid < 250) {
        float v = vstart[seg][o], ps = 0.f;
#pragma unroll
        for (int j = 0; j < 20; ++j) {
            const int t = seg * 20 + j;
            v += (Io[t * NO + o] - v) * 0.1f;
            const float sv = sigmoid5(v);
            out[(size_t)b * (NO * T_) + (size_t)o * T_ + t] = sv;
            ps += sv;
        }
        psum[seg][o] = ps;
    }
    __syncthreads();
    if (tid < NO) {
        float tot = 0.f;
#pragma unroll
        for (int sg = 0; sg < 25; ++sg) tot += psum[sg][tid];
        out[(size_t)(B_ * NO) * T_ + b * NO + tid] = tot * (1.0f / T_);
    }
}

extern "C" void kernel_launch(void* const* d_in, const int* in_sizes, int n_in,
                              void* d_out, int out_size, void* d_ws, size_t ws_size,
                              hipStream_t stream) {
    (void)in_sizes; (void)n_in; (void)out_size; (void)ws_size;
    const float* spikes = (const float*)d_in[0];   // [128][784][500]
    const float* w_ih   = (const float*)d_in[1];   // [784][256]
    const float* w_ho   = (const float*)d_in[2];   // [256][10]
    float* out = (float*)d_out;

    float* wrelu = (float*)d_ws;                            // 10KB @0
    u16*   Bt    = (u16*)((char*)d_ws + 16384);             // 448KB
    u16*   Ih    = (u16*)((char*)d_ws + 524288);            // 33.55MB

    convert_W  <<<NSLAB * 128 + 1, 256, 0, stream>>>(w_ih, w_ho, Bt, wrelu);
    gemm_hidden<<<256, 512, 0, stream>>>(spikes, Bt, Ih);
    scan_h     <<<4096, 512, 0, stream>>>(Ih);
    out_fused  <<<B_, 512, 0, stream>>>(Ih, wrelu, out);
}

// Round 9
// 118.039 us; speedup vs baseline: 1.6892x; 1.3466x over previous
//
#include <hip/hip_runtime.h>

// LIF net on MI355X.  R9: high-occupancy read-once GEMM.
//  1. convert_W: Bt[25][256][32] bf16 (relu, slot-swizzled, K-pad 800) + wrelu
//  2. gemm_hidden: 512 blocks (b, t-quarter), tile 128m x 256n, BK=32,
//     48KB LDS dbuf -> 2 blocks/CU, acc 64 VGPR, A reg-prefetch 1 ahead,
//     B gload16 from L2-resident Bt.  Epilogue transpose -> Ih[b][h][512].
//  3. scan_h: wave-per-row parallel LIF scan (shfl_up affine composition)
//  4. out_fused: per-b VALU dot (K=256,N=10) -> LDS -> segmented v_o scan
// ws: wrelu @0 (10KB) | Bt @16KB (400KB) | Ih @512KB (33.55MB)

typedef __attribute__((ext_vector_type(4))) float  floatx4;
typedef __attribute__((ext_vector_type(8))) short  shortx8;
typedef unsigned short u16;
typedef unsigned int   u32;

#define B_   128
#define NIN  784
#define NH   256
#define NO   10
#define T_   500
#define NK   25            // K padded to 800, slabs of 32

__device__ __forceinline__ u16 f2bf(float f) {
    union { float f; u32 u; } x; x.f = f;
    u32 r = x.u + 0x7FFFu + ((x.u >> 16) & 1u);   // RNE
    return (u16)(r >> 16);
}
__device__ __forceinline__ float bf2f(u16 u) {
    union { u32 u; float f; } x; x.u = ((u32)u) << 16; return x.f;
}
__device__ __forceinline__ float sigmoid5(float v) {
    return 1.0f / (1.0f + __expf(-5.0f * (v - 1.0f)));
}

__device__ __forceinline__ void gload16(const u16* g, u16* l) {
    __builtin_amdgcn_global_load_lds(
        (const __attribute__((address_space(1))) unsigned int*)(const void*)g,
        (__attribute__((address_space(3))) unsigned int*)(void*)l, 16, 0, 0);
}

// ---------- Pre-pass: Bt[kt][n][slot*8 + k&7] bf16 + wrelu ----------
// slot(n, oct) = oct ^ (n&3) ^ ((n>>2)&3); frag read at slot_r = lg^... -> oct=lg.
__global__ void convert_W(const float* __restrict__ w_ih,
                          const float* __restrict__ w_ho,
                          u16* __restrict__ Bt, float* __restrict__ wrelu) {
    if (blockIdx.x == NK * 32) {
        for (int i = threadIdx.x; i < NH * NO; i += 256)
            wrelu[i] = fmaxf(0.f, w_ho[i]);
        return;
    }
    const int k = blockIdx.x;           // 0..799
    const int n = threadIdx.x;          // 0..255
    const float f = (k < NIN) ? fmaxf(0.f, w_ih[k * NH + n]) : 0.f;
    const int kt = k >> 5, kk = k & 31;
    const int slot = (kk >> 3) ^ (n & 3) ^ ((n >> 2) & 3);
    Bt[(size_t)kt * 8192 + n * 32 + slot * 8 + (kk & 7)] = f2bf(f);
}

// ---------- hidden GEMM ----------
// 512 blocks = (b, tq); 512 thr = 8 waves (2 wm x 4 wn), wave tile 64x64
// (4x4 frags, 64 acc VGPR).  LDS 48KB: As dbuf 2x8KB + Bs dbuf 2x16KB.
__global__ __launch_bounds__(512, 4) void gemm_hidden(
    const float* __restrict__ spikes,   // [128][784][500] f32
    const u16* __restrict__ Bt,         // [25][256][32] bf16 swizzled
    u16* __restrict__ Ih)               // [128][256][512] bf16
{
    __shared__ u16 SH[24576];           // 48KB
    u16* AS0 = SH;                      // 4096 u16 = 8KB
    u16* AS1 = SH + 4096;
    u16* BS0 = SH + 8192;               // 8192 u16 = 16KB
    u16* BS1 = SH + 16384;

    const int tid = threadIdx.x;
    const int b   = blockIdx.x >> 2;
    const int tq  = blockIdx.x & 3;
    const int t0  = tq * 128;

    // A staging: thread = (kp 0..15, tg 0..31): k = 2kp,2kp+1 at t = t0+tg*4..+3
    const int kp = tid >> 5, tg = tid & 31;
    const int tloc = t0 + tg * 4;
    const int koff = (2 * kp) & 7;      // within-octet k offset (even)
    const int oct  = kp >> 2;
    const bool t_ok = (tloc <= 496);    // float4 t..t+3 < 500
    const float* sbase = spikes + (size_t)b * (NIN * T_) + tloc;

    // MFMA roles
    const int lane = tid & 63, wid = tid >> 6;
    const int wm = wid >> 2, wn = wid & 3;             // wm 0..1, wn 0..3
    const int lg = lane >> 4, lr = lane & 15;
    int aOff[4], bOff[4];
#pragma unroll
    for (int mi = 0; mi < 4; ++mi) {
        const int m = wm * 64 + mi * 16 + lr;
        aOff[mi] = m * 32 + ((lg ^ (m & 3) ^ ((m >> 2) & 3)) << 3);
    }
#pragma unroll
    for (int ni = 0; ni < 4; ++ni) {
        const int n = wn * 64 + ni * 16 + lr;
        bOff[ni] = n * 32 + ((lg ^ (n & 3) ^ ((n >> 2) & 3)) << 3);
    }

    floatx4 acc[4][4];
#pragma unroll
    for (int i = 0; i < 4; ++i)
#pragma unroll
        for (int j = 0; j < 4; ++j) acc[i][j] = (floatx4)0.f;

#define LOADA(v0, v1, itv) {                                                   \
        const int gk = (itv) * 32 + 2 * kp;                                    \
        const bool ok0 = t_ok && (gk < NIN);                                   \
        const bool ok1 = t_ok && (gk + 1 < NIN);                               \
        const float* p0 = ok0 ? (sbase + (size_t)gk * T_) : sbase;             \
        const float* p1 = ok1 ? (sbase + (size_t)(gk + 1) * T_) : sbase;       \
        floatx4 u0 = *(const floatx4*)p0;                                      \
        floatx4 u1 = *(const floatx4*)p1;                                      \
        v0 = ok0 ? u0 : (floatx4)0.f;                                          \
        v1 = ok1 ? u1 : (floatx4)0.f; }

#define WRITEA(ASX, v0, v1) { _Pragma("unroll") for (int j = 0; j < 4; ++j) {  \
        const int m = tg * 4 + j;                                              \
        const int slot = oct ^ (m & 3) ^ ((m >> 2) & 3);                       \
        const u32 pk = (u32)f2bf(v0[j]) | ((u32)f2bf(v1[j]) << 16);            \
        *(u32*)&(ASX)[m * 32 + slot * 8 + koff] = pk; } }

#define STAGEB(BSX, itv) { const u16* src = Bt + (size_t)(itv) * 8192;         \
        gload16(src + tid * 8,        (BSX) + tid * 8);                        \
        gload16(src + 4096 + tid * 8, (BSX) + 4096 + tid * 8); }

#define MFMAIT(ASX, BSX) { shortx8 af[4], bf[4];                               \
        _Pragma("unroll") for (int mi = 0; mi < 4; ++mi)                       \
            af[mi] = *(const shortx8*)&(ASX)[aOff[mi]];                        \
        _Pragma("unroll") for (int ni = 0; ni < 4; ++ni)                       \
            bf[ni] = *(const shortx8*)&(BSX)[bOff[ni]];                        \
        _Pragma("unroll") for (int mi = 0; mi < 4; ++mi)                       \
        _Pragma("unroll") for (int ni = 0; ni < 4; ++ni)                       \
            acc[mi][ni] = __builtin_amdgcn_mfma_f32_16x16x32_bf16(             \
                af[mi], bf[ni], acc[mi][ni], 0, 0, 0); }

    floatx4 vaP0, vaP1, vaQ0, vaQ1;

    // prologue
    LOADA(vaP0, vaP1, 0);
    WRITEA(AS0, vaP0, vaP1);            // waits only vaP's vmcnt
    STAGEB(BS0, 0);
    LOADA(vaQ0, vaQ1, 1);
    __syncthreads();

    // body: 24 iters, manually 2-unrolled so va ping-pong is compile-time
    for (int it = 0; it < 24; it += 2) {
        // iter it (even): cur = AS0/BS0, next = AS1/BS1
        WRITEA(AS1, vaQ0, vaQ1);
        STAGEB(BS1, it + 1);
        LOADA(vaP0, vaP1, it + 2);
        MFMAIT(AS0, BS0);
        __syncthreads();
        // iter it+1 (odd)
        WRITEA(AS0, vaP0, vaP1);
        STAGEB(BS0, it + 2);
        LOADA(vaQ0, vaQ1, it + 3);
        MFMAIT(AS1, BS1);
        __syncthreads();
    }
    MFMAIT(AS0, BS0);                   // iter 24
    __syncthreads();                    // LDS reads done; SH free for Cs

    // epilogue: two m-halves via Cs[256][64] (32KB) -> Ih[b][n][t0 + h*64 + m]
    u16* Cs = SH;
#pragma unroll
    for (int h = 0; h < 2; ++h) {
        if (wm == h) {
#pragma unroll
            for (int mi = 0; mi < 4; ++mi)
#pragma unroll
                for (int rr = 0; rr < 2; ++rr) {
                    const int mloc = mi * 16 + lg * 4 + rr * 2;
#pragma unroll
                    for (int ni = 0; ni < 4; ++ni) {
                        const int n = wn * 64 + ni * 16 + lr;
                        const u32 pk = (u32)f2bf(acc[mi][ni][rr * 2]) |
                                       ((u32)f2bf(acc[mi][ni][rr * 2 + 1]) << 16);
                        *(u32*)&Cs[n * 64 + (mloc ^ ((n & 7) << 3))] = pk;
                    }
                }
        }
        __syncthreads();
        {
            const int n = tid >> 1, mh = tid & 1;
            u16* gdst = Ih + ((size_t)b * 256 + n) * 512 + t0 + h * 64 + mh * 32;
#pragma unroll
            for (int j = 0; j < 4; ++j) {
                const uint4 v = *(const uint4*)&Cs[n * 64 + ((mh * 32 + 8 * j) ^ ((n & 7) << 3))];
                *(uint4*)(gdst + 8 * j) = v;
            }
        }
        __syncthreads();
    }
#undef LOADA
#undef WRITEA
#undef STAGEB
#undef MFMAIT
}

// ---------- parallel hidden LIF scan (in place) ----------
__global__ __launch_bounds__(512) void scan_h(u16* __restrict__ Ih) {
    const int lane = threadIdx.x & 63;
    const int row  = blockIdx.x * 8 + (threadIdx.x >> 6);
    u16* p = Ih + (size_t)row * 512 + lane * 8;
    shortx8 xv = *(const shortx8*)p;
    float I[8];
#pragma unroll
    for (int j = 0; j < 8; ++j) I[j] = bf2f((u16)xv[j]);
    float z = 0.f;
#pragma unroll
    for (int j = 0; j < 8; ++j) z += (I[j] - z) * 0.1f;
    float A = 0.43046721f, Bv = z;                 // 0.9^8
#pragma unroll
    for (int d = 1; d < 64; d <<= 1) {
        const float Au = __shfl_up(A, d);
        const float Bu = __shfl_up(Bv, d);
        if (lane >= d) { Bv = fmaf(A, Bu, Bv); A *= Au; }
    }
    float v = __shfl_up(Bv, 1);
    if (lane == 0) v = 0.f;
#pragma unroll
    for (int j = 0; j < 8; ++j) {
        v += (I[j] - v) * 0.1f;
        xv[j] = (short)f2bf(sigmoid5(v));
    }
    *(shortx8*)p = xv;
}

// ---------- output dot + segmented v_o scan ----------
__global__ __launch_bounds__(512) void out_fused(
    const u16* __restrict__ s,          // [128][256][512] bf16
    const float* __restrict__ wr,       // [256][10] relu'd f32
    float* __restrict__ out)
{
    __shared__ float Io[T_ * NO];
    __shared__ float vend[25][NO], vstart[25][NO], psum[25][NO];
    const int b = blockIdx.x, tid = threadIdx.x;

    float acc[NO];
#pragma unroll
    for (int o = 0; o < NO; ++o) acc[o] = 0.f;
    const u16* sb = s + (size_t)b * NH * 512 + tid;
#pragma unroll 2
    for (int h = 0; h < NH; ++h) {
        const float sv = bf2f(sb[h * 512]);
#pragma unroll
        for (int o = 0; o < NO; ++o) acc[o] = fmaf(sv, wr[h * NO + o], acc[o]);
    }
    if (tid < T_) {
#pragma unroll
        for (int o = 0; o < NO; ++o) Io[tid * NO + o] = acc[o];
    }
    __syncthreads();

    const int seg = tid / NO, o = tid - seg * NO;
    if (tid < 250) {
        float v = 0.f;
#pragma unroll
        for (int j = 0; j < 20; ++j)
            v += (Io[(seg * 20 + j) * NO + o] - v) * 0.1f;
        vend[seg][o] = v;
    }
    __syncthreads();
    if (tid < NO) {
        float vs = 0.f;
#pragma unroll
        for (int sg = 0; sg < 25; ++sg) {
            vstart[sg][tid] = vs;
            vs = vend[sg][tid] + 0.12157665459f * vs;   // 0.9^20
        }
    }
    __syncthreads();
    if (tid < 250) {
        float v = vstart[seg][o], ps = 0.f;
#pragma unroll
        for (int j = 0; j < 20; ++j) {
            const int t = seg * 20 + j;
            v += (Io[t * NO + o] - v) * 0.1f;
            const float sv = sigmoid5(v);
            out[(size_t)b * (NO * T_) + (size_t)o * T_ + t] = sv;
            ps += sv;
        }
        psum[seg][o] = ps;
    }
    __syncthreads();
    if (tid < NO) {
        float tot = 0.f;
#pragma unroll
        for (int sg = 0; sg < 25; ++sg) tot += psum[sg][tid];
        out[(size_t)(B_ * NO) * T_ + b * NO + tid] = tot * (1.0f / T_);
    }
}

extern "C" void kernel_launch(void* const* d_in, const int* in_sizes, int n_in,
                              void* d_out, int out_size, void* d_ws, size_t ws_size,
                              hipStream_t stream) {
    (void)in_sizes; (void)n_in; (void)out_size; (void)ws_size;
    const float* spikes = (const float*)d_in[0];   // [128][784][500]
    const float* w_ih   = (const float*)d_in[1];   // [784][256]
    const float* w_ho   = (const float*)d_in[2];   // [256][10]
    float* out = (float*)d_out;

    float* wrelu = (float*)d_ws;                            // 10KB @0
    u16*   Bt    = (u16*)((char*)d_ws + 16384);             // 400KB
    u16*   Ih    = (u16*)((char*)d_ws + 524288);            // 33.55MB

    convert_W  <<<NK * 32 + 1, 256, 0, stream>>>(w_ih, w_ho, Bt, wrelu);
    gemm_hidden<<<512, 512, 0, stream>>>(spikes, Bt, Ih);
    scan_h     <<<4096, 512, 0, stream>>>(Ih);
    out_fused  <<<B_, 512, 0, stream>>>(Ih, wrelu, out);
}